// Round 1
// baseline (268.773 us; speedup 1.0000x reference)
//
#include <hip/hip_runtime.h>
#include <hip/hip_bf16.h>

#define DIM    1024
#define HEADS  16
#define DH     64
#define SEG    512
#define PMEMN  16
#define TOK    8192        // 2*4096 tokens = 16 segments * 512
#define NQKV   3072
#define JPAD   544         // PMEM + SEG + 16 zero-pad (17 tiles of 32)
#define NSH    256         // 16 segments * 16 heads
#define VTS    129         // v-transpose LDS row stride (odd -> no 16-way bank conflict)

typedef __hip_bfloat16 bf16;
typedef __attribute__((ext_vector_type(8))) short short8;   // 8 bf16 = 4 VGPRs
typedef __attribute__((ext_vector_type(4))) float floatx4;  // MFMA C/D frag

__device__ __forceinline__ short8 ld_frag(const bf16* p) {
    return *(const short8*)p;
}
__device__ __forceinline__ floatx4 mfma16(short8 a, short8 b, floatx4 c) {
    return __builtin_amdgcn_mfma_f32_16x16x32_bf16(a, b, c, 0, 0, 0);
}
__device__ __forceinline__ void st_out(bf16* p, float v) { *p = __float2bfloat16(v); }
__device__ __forceinline__ void st_out(float* p, float v) { *p = v; }
// async global->LDS DMA, 16 B per lane; LDS dest must be wave base + lane*16
__device__ __forceinline__ void g2lds16(const bf16* g, bf16* l) {
    __builtin_amdgcn_global_load_lds((const __attribute__((address_space(1))) void*)g,
                                     (__attribute__((address_space(3))) void*)l, 16, 0, 0);
}

// ---------------- RMSNorm: fp32 in -> bf16 normalized ----------------
__global__ void rmsnorm_kernel(const float* __restrict__ x, const float* __restrict__ wgt,
                               bf16* __restrict__ xn) {
    int row = blockIdx.x;
    int tid = threadIdx.x;              // 256 threads, 4 floats each
    const float4* xr = (const float4*)(x + (long)row * DIM);
    float4 v = xr[tid];
    float ss = v.x * v.x + v.y * v.y + v.z * v.z + v.w * v.w;
    #pragma unroll
    for (int off = 32; off; off >>= 1) ss += __shfl_xor(ss, off);
    __shared__ float red[4];
    if ((tid & 63) == 0) red[tid >> 6] = ss;
    __syncthreads();
    float tot = red[0] + red[1] + red[2] + red[3];
    float sc = rsqrtf(tot * (1.0f / DIM) + 1.1920929e-07f);
    const float4* wr = (const float4*)wgt;
    float4 w4 = wr[tid];
    bf16* o = xn + (long)row * DIM + tid * 4;
    o[0] = __float2bfloat16(v.x * sc * w4.x);
    o[1] = __float2bfloat16(v.y * sc * w4.y);
    o[2] = __float2bfloat16(v.z * sc * w4.z);
    o[3] = __float2bfloat16(v.w * sc * w4.w);
}

// ---- merged transpose + cast: wqkv [1024][3072] and wout [1024][1024] -> bf16 [C][R] ----
__global__ void transpose_w2(const float* __restrict__ wqkv, const float* __restrict__ wout,
                             bf16* __restrict__ wqkvT, bf16* __restrict__ woutT) {
    __shared__ float tile[32][33];
    int bx = blockIdx.x;
    const float* in; bf16* out; int C, c0;
    if (bx < 96) { in = wqkv; out = wqkvT; C = NQKV; c0 = bx * 32; }
    else         { in = wout; out = woutT; C = DIM;  c0 = (bx - 96) * 32; }
    const int R = DIM;
    int r0 = blockIdx.y * 32;
    int tx = threadIdx.x, ty = threadIdx.y;      // (32,8)
    #pragma unroll
    for (int i = 0; i < 4; i++)
        tile[ty + i * 8][tx] = in[(long)(r0 + ty + i * 8) * C + c0 + tx];
    __syncthreads();
    #pragma unroll
    for (int i = 0; i < 4; i++)
        out[(long)(c0 + ty + i * 8) * R + r0 + tx] = __float2bfloat16(tile[tx][ty + i * 8]);
}

// ---- rope table: rt[sl][dh] = (cos, sin) of sl * 10000^(-(dh>>1)/32) ----
__global__ void rope_table(float2* __restrict__ rt) {
    int gid = blockIdx.x * 256 + threadIdx.x;   // SEG*DH = 32768 entries
    int sl = gid >> 6, dh = gid & 63;
    int pr = dh >> 1;
    float invf = __expf(-(float)pr * (9.210340371976184f / 32.0f));
    float ang = (float)sl * invf;
    float sn, cs;
    sincosf(ang, &sn, &cs);    // precise: table is tiny, computed once per launch
    rt[gid] = make_float2(cs, sn);
}

// ------- plain GEMM (out-projection): C[M][N] = A[M][K]*Bt[N][K]^T, BK=64, swizzled -------
template <typename OT>
__global__ __launch_bounds__(256)
void gemm_bt(const bf16* __restrict__ A, const bf16* __restrict__ Bt,
             OT* __restrict__ C, int M, int N, int K) {
    __shared__ __align__(16) bf16 As[128 * 64];
    __shared__ __align__(16) bf16 Bs[128 * 64];
    const int tid = threadIdx.x;
    const int wv = tid >> 6;
    const int lane = tid & 63;
    const int quad = lane >> 4, l15 = lane & 15;
    const int wm = (wv >> 1) * 64, wn = (wv & 1) * 64;
    const int bm = blockIdx.x, bn = blockIdx.y;

    const int srow = tid >> 3;
    const int sgch = (tid & 7) ^ (srow & 7);
    const bf16* Ag = A + (long)(bm * 128 + srow) * K + sgch * 8;
    const bf16* Bg = Bt + (long)(bn * 128 + srow) * K + sgch * 8;
    const long row32 = (long)32 * K;

    const int rx0 = ((0 + quad) ^ (l15 & 7)) * 8;
    const int rx1 = ((4 + quad) ^ (l15 & 7)) * 8;

    floatx4 acc[4][4] = {};

    for (int k0 = 0; k0 < K; k0 += 64) {
        __syncthreads();
        #pragma unroll
        for (int i = 0; i < 4; i++) {
            g2lds16(Ag + i * row32 + k0, As + i * 2048 + tid * 8);
            g2lds16(Bg + i * row32 + k0, Bs + i * 2048 + tid * 8);
        }
        __syncthreads();
        #pragma unroll
        for (int kk = 0; kk < 2; kk++) {
            const int rx = kk ? rx1 : rx0;
            short8 af[4], bfr[4];
            #pragma unroll
            for (int i = 0; i < 4; i++) af[i] = ld_frag(&As[(wm + i * 16 + l15) * 64 + rx]);
            #pragma unroll
            for (int j = 0; j < 4; j++) bfr[j] = ld_frag(&Bs[(wn + j * 16 + l15) * 64 + rx]);
            #pragma unroll
            for (int i = 0; i < 4; i++)
                #pragma unroll
                for (int j = 0; j < 4; j++)
                    acc[i][j] = mfma16(af[i], bfr[j], acc[i][j]);
        }
    }
    #pragma unroll
    for (int i = 0; i < 4; i++)
        #pragma unroll
        for (int j = 0; j < 4; j++) {
            int row = bm * 128 + wm + i * 16 + quad * 4;
            int col = bn * 128 + wn + j * 16 + l15;
            #pragma unroll
            for (int r = 0; r < 4; r++)
                st_out(&C[(long)(row + r) * N + col], acc[i][j][r]);
        }
}

// ------- QKV GEMM with fused epilogue: rope(q)->qbuf, rope(k)->kpad, v->origv+vtpad -------
__global__ __launch_bounds__(256)
void gemm_qkv_ep(const bf16* __restrict__ A, const bf16* __restrict__ Bt,
                 const float2* __restrict__ rt,
                 bf16* __restrict__ qbuf, bf16* __restrict__ kpad,
                 bf16* __restrict__ vtpad, float* __restrict__ origv) {
    const int K = DIM, N = NQKV;
    __shared__ __align__(16) bf16 SM[128 * 136];   // 34816 B; K-loop uses first 32 KB
    bf16* As = SM;
    bf16* Bs = SM + 128 * 64;
    const int tid = threadIdx.x;
    const int wv = tid >> 6;
    const int lane = tid & 63;
    const int quad = lane >> 4, l15 = lane & 15;
    const int wm = (wv >> 1) * 64, wn = (wv & 1) * 64;
    const int bm = blockIdx.x, bn = blockIdx.y;

    const int strow = tid >> 3;
    const int sgch = (tid & 7) ^ (strow & 7);
    const bf16* Ag = A + (long)(bm * 128 + strow) * K + sgch * 8;
    const bf16* Bg = Bt + (long)(bn * 128 + strow) * K + sgch * 8;
    const long row32 = (long)32 * K;

    const int rx0 = ((0 + quad) ^ (l15 & 7)) * 8;
    const int rx1 = ((4 + quad) ^ (l15 & 7)) * 8;

    floatx4 acc[4][4] = {};

    for (int k0 = 0; k0 < K; k0 += 64) {
        __syncthreads();
        #pragma unroll
        for (int i = 0; i < 4; i++) {
            g2lds16(Ag + i * row32 + k0, As + i * 2048 + tid * 8);
            g2lds16(Bg + i * row32 + k0, Bs + i * 2048 + tid * 8);
        }
        __syncthreads();
        #pragma unroll
        for (int kk = 0; kk < 2; kk++) {
            const int rx = kk ? rx1 : rx0;
            short8 af[4], bfr[4];
            #pragma unroll
            for (int i = 0; i < 4; i++) af[i] = ld_frag(&As[(wm + i * 16 + l15) * 64 + rx]);
            #pragma unroll
            for (int j = 0; j < 4; j++) bfr[j] = ld_frag(&Bs[(wn + j * 16 + l15) * 64 + rx]);
            #pragma unroll
            for (int i = 0; i < 4; i++)
                #pragma unroll
                for (int j = 0; j < 4; j++)
                    acc[i][j] = mfma16(af[i], bfr[j], acc[i][j]);
        }
    }

    const int tok0 = bm * 128;
    const int seg = tok0 >> 9;          // block fully inside one segment
    const int s0 = tok0 & 511;

    if (bn < 16) {
        // ---- q or k block: rope via precomputed (cos,sin) table; pair partner in lane l15^1 ----
        const bool isq = (bn < 8);
        #pragma unroll
        for (int j = 0; j < 4; j++) {
            int col = bn * 128 + wn + j * 16 + l15;
            int dcol = col & 1023;                   // within q or k
            int h = dcol >> 6, dh = dcol & 63;
            const bool odd = dh & 1;
            #pragma unroll
            for (int i = 0; i < 4; i++)
                #pragma unroll
                for (int r = 0; r < 4; r++) {
                    int sl = s0 + wm + i * 16 + quad * 4 + r;   // s within segment
                    float2 cs = rt[sl * 64 + dh];               // L2-resident, coalesced
                    float v = acc[i][j][r];
                    float px = __shfl_xor(v, 1);
                    float y = odd ? fmaf(v, cs.x,  px * cs.y)
                                  : fmaf(v, cs.x, -px * cs.y);
                    if (isq) {
                        qbuf[(long)(tok0 + wm + i * 16 + quad * 4 + r) * DIM + dcol] =
                            __float2bfloat16(y * 0.125f);        // fold DH^-0.5 (exact)
                    } else {
                        kpad[(((long)(seg * 16 + h) * JPAD) + PMEMN + sl) * DH + dh] =
                            __float2bfloat16(y);
                    }
                }
        }
    } else {
        // ---- v block: origv fp32 direct + LDS transpose -> vtpad ----
        const int vq = bn - 16;
        #pragma unroll
        for (int j = 0; j < 4; j++) {
            int lc = wn + j * 16 + l15;
            int vcol = vq * 128 + lc;
            int h = vcol >> 6, dh = vcol & 63;
            #pragma unroll
            for (int i = 0; i < 4; i++)
                #pragma unroll
                for (int r = 0; r < 4; r++) {
                    int sl = s0 + wm + i * 16 + quad * 4 + r;
                    origv[((long)(seg * 16 + h) * SEG + sl) * DH + dh] = acc[i][j][r];
                }
        }
        __syncthreads();   // all waves done reading As/Bs
        // row stride VTS=129 (odd): column read below spreads over 8 banks (2-way, free)
        #pragma unroll
        for (int i = 0; i < 4; i++)
            #pragma unroll
            for (int j = 0; j < 4; j++)
                #pragma unroll
                for (int r = 0; r < 4; r++)
                    SM[(wm + i * 16 + quad * 4 + r) * VTS + wn + j * 16 + l15] =
                        __float2bfloat16(acc[i][j][r]);
        __syncthreads();
        #pragma unroll
        for (int it = 0; it < 8; it++) {
            int cid = it * 256 + tid;
            int orow = cid >> 4;          // local v-col 0..127
            int tch = cid & 15;           // token chunk of 8
            int vcol = vq * 128 + orow;
            int h = vcol >> 6, dh = vcol & 63;
            short8 pk;
            #pragma unroll
            for (int k = 0; k < 8; k++) {
                bf16 t = SM[(tch * 8 + k) * VTS + orow];
                pk[k] = __builtin_bit_cast(short, t);
            }
            *(short8*)&vtpad[(((long)(seg * 16 + h) * DH + dh) * JPAD) + PMEMN + s0 + tch * 8] = pk;
        }
    }
}

// ------------- pmem rows into kpad/vtpad + zero tail pad -------------
__global__ void fill_pmem_pad(const float* __restrict__ pmem, bf16* __restrict__ kpad,
                              bf16* __restrict__ vtpad) {
    int gid = blockIdx.x * 256 + threadIdx.x;
    int dh = gid & 63, j = (gid >> 6) & 15, sh = gid >> 10;
    int h = sh & 15;
    float kv = pmem[((0 * HEADS + h) * PMEMN + j) * DH + dh];
    float vv = pmem[((1 * HEADS + h) * PMEMN + j) * DH + dh];
    kpad[((long)sh * JPAD + j) * DH + dh] = __float2bfloat16(kv);
    vtpad[((long)sh * DH + dh) * JPAD + j] = __float2bfloat16(vv);
    kpad[((long)sh * JPAD + PMEMN + SEG + j) * DH + dh] = __float2bfloat16(0.0f);
    vtpad[((long)sh * DH + dh) * JPAD + PMEMN + SEG + j] = __float2bfloat16(0.0f);
}

// ------- flash attention v3: 1 wave = 32 q rows, NO block barriers in K-loop -------
__global__ __launch_bounds__(256, 3)
void flash_attn(const bf16* __restrict__ qbuf, const bf16* __restrict__ kpad,
                const bf16* __restrict__ vtpad, bf16* __restrict__ attn_out) {
    const int bid = blockIdx.x;
    const int sh = bid & (NSH - 1);
    const int qblk = bid >> 8;
    const int wv = threadIdx.x >> 6;
    const int lane = threadIdx.x & 63;
    const int quad = lane >> 4, l15 = lane & 15;
    const int qr0 = qblk * 128 + wv * 32;
    const int bw = sh >> 4, h = sh & 15;

    __shared__ __align__(16) short pbuf[4][32 * 32];   // per-wave P tile
    short* pb = pbuf[wv];

    const bf16* qr_g0 = qbuf + (long)(bw * SEG + qr0 + l15) * DIM + h * DH;
    const bf16* qr_g1 = qbuf + (long)(bw * SEG + qr0 + 16 + l15) * DIM + h * DH;
    short8 aq[2][2] = {{ld_frag(qr_g0 + quad * 8), ld_frag(qr_g0 + 32 + quad * 8)},
                       {ld_frag(qr_g1 + quad * 8), ld_frag(qr_g1 + 32 + quad * 8)}};

    // ones B-fragment: B[k][0]=1 -> D[:,0] = row-sum of P
    const short bf16one = (short)0x3F80;
    short8 onesB;
    #pragma unroll
    for (int i = 0; i < 8; i++) onesB[i] = (l15 == 0) ? bf16one : (short)0;

    float mrow[2][4];
    floatx4 o[2][4] = {};
    floatx4 lac[2] = {};
    #pragma unroll
    for (int g = 0; g < 2; g++)
        #pragma unroll
        for (int r = 0; r < 4; r++) mrow[g][r] = -1e30f;

    const bf16* kb = kpad + (long)sh * JPAD * DH;
    const bf16* vbp = vtpad + (long)sh * DH * JPAD;

    const int ntiles = (qr0 + 47) / 32 + 1;

    short8 kf[4];
    {
        const bf16* kr0 = kb + (long)l15 * DH;
        const bf16* kr1 = kb + (long)(16 + l15) * DH;
        kf[0] = ld_frag(kr0 + quad * 8);  kf[1] = ld_frag(kr0 + 32 + quad * 8);
        kf[2] = ld_frag(kr1 + quad * 8);  kf[3] = ld_frag(kr1 + 32 + quad * 8);
    }

    for (int jt = 0; jt < ntiles; ++jt) {
        const int j0 = jt * 32;
        short8 bv[4];
        #pragma unroll
        for (int n = 0; n < 4; n++)
            bv[n] = ld_frag(vbp + (long)(n * 16 + l15) * JPAD + j0 + quad * 8);

        floatx4 sc[2][2];
        #pragma unroll
        for (int g = 0; g < 2; g++) {
            sc[g][0] = mfma16(aq[g][1], kf[1], mfma16(aq[g][0], kf[0], floatx4{}));
            sc[g][1] = mfma16(aq[g][1], kf[3], mfma16(aq[g][0], kf[2], floatx4{}));
        }
        {
            const int jn = (jt + 1 < ntiles) ? j0 + 32 : j0;
            const bf16* kr0 = kb + (long)(jn + l15) * DH;
            const bf16* kr1 = kb + (long)(jn + 16 + l15) * DH;
            kf[0] = ld_frag(kr0 + quad * 8);  kf[1] = ld_frag(kr0 + 32 + quad * 8);
            kf[2] = ld_frag(kr1 + quad * 8);  kf[3] = ld_frag(kr1 + 32 + quad * 8);
        }

        float alpha[2][4];
        #pragma unroll
        for (int g = 0; g < 2; g++) {
            #pragma unroll
            for (int r = 0; r < 4; r++) {
                int qi = qr0 + g * 16 + quad * 4 + r;
                int ja = j0 + l15;
                int jb = j0 + 16 + l15;
                float va  = ((ja < PMEMN) || (ja - PMEMN <= qi)) ? sc[g][0][r] : -1e30f;
                float vb2 = ((jb < PMEMN) || (jb - PMEMN <= qi)) ? sc[g][1][r] : -1e30f;
                float rm = fmaxf(va, vb2);
                #pragma unroll
                for (int off = 1; off < 16; off <<= 1) rm = fmaxf(rm, __shfl_xor(rm, off));
                float mn = fmaxf(mrow[g][r], rm);
                alpha[g][r] = __expf(mrow[g][r] - mn);
                mrow[g][r] = mn;
                float p0 = __expf(va - mn);
                float p1 = __expf(vb2 - mn);
                pb[(g * 16 + quad * 4 + r) * 32 + l15]      = __builtin_bit_cast(short, __float2bfloat16(p0));
                pb[(g * 16 + quad * 4 + r) * 32 + 16 + l15] = __builtin_bit_cast(short, __float2bfloat16(p1));
            }
        }
        __asm__ volatile("" ::: "memory");
        short8 pa0, pa1;
        __builtin_memcpy(&pa0, &pb[l15 * 32 + quad * 8], 16);
        __builtin_memcpy(&pa1, &pb[(16 + l15) * 32 + quad * 8], 16);
        __asm__ volatile("" ::: "memory");
        #pragma unroll
        for (int r = 0; r < 4; r++) { lac[0][r] *= alpha[0][r]; lac[1][r] *= alpha[1][r]; }
        lac[0] = mfma16(pa0, onesB, lac[0]);
        lac[1] = mfma16(pa1, onesB, lac[1]);
        #pragma unroll
        for (int n = 0; n < 4; n++) {
            #pragma unroll
            for (int r = 0; r < 4; r++) { o[0][n][r] *= alpha[0][r]; o[1][n][r] *= alpha[1][r]; }
            o[0][n] = mfma16(pa0, bv[n], o[0][n]);
            o[1][n] = mfma16(pa1, bv[n], o[1][n]);
        }
    }
    #pragma unroll
    for (int g = 0; g < 2; g++) {
        bf16* orow = attn_out + (long)(bw * SEG + qr0 + g * 16 + quad * 4) * DIM + h * DH;
        #pragma unroll
        for (int r = 0; r < 4; r++) {
            float lsum = __shfl(lac[g][r], (lane & 48));
            float inv = 1.0f / lsum;
            #pragma unroll
            for (int n = 0; n < 4; n++)
                orow[(long)r * DIM + n * 16 + l15] = __float2bfloat16(o[g][n][r] * inv);
        }
    }
}

extern "C" void kernel_launch(void* const* d_in, const int* in_sizes, int n_in,
                              void* d_out, int out_size, void* d_ws, size_t ws_size,
                              hipStream_t stream) {
    const float* seq    = (const float*)d_in[0];
    const float* norm_w = (const float*)d_in[1];
    const float* w_qkv  = (const float*)d_in[2];
    const float* w_out  = (const float*)d_in[3];
    const float* pmem   = (const float*)d_in[4];
    // Reference outputs are FLOAT32: d_out = [out, orig_v] fp32.
    float* out   = (float*)d_out;
    float* origv = out + (long)TOK * DIM;

    char* p = (char*)d_ws;
    bf16* xn     = (bf16*)p; p += (long)TOK * DIM * 2;
    bf16* wqkvT  = (bf16*)p; p += (long)NQKV * DIM * 2;
    bf16* woutT  = (bf16*)p; p += (long)DIM * DIM * 2;
    bf16* qbuf   = (bf16*)p; p += (long)TOK * DIM * 2;
    bf16* kpadb  = (bf16*)p; p += (long)NSH * JPAD * DH * 2;
    bf16* vtpadb = (bf16*)p; p += (long)NSH * DH * JPAD * 2;
    float2* rtab = (float2*)p; p += (long)SEG * DH * sizeof(float2);
    bf16* attno  = xn;   // xn dead after QKV GEMM

    rmsnorm_kernel<<<TOK, 256, 0, stream>>>(seq, norm_w, xn);
    transpose_w2<<<dim3(128, 32), dim3(32, 8), 0, stream>>>(w_qkv, w_out, wqkvT, woutT);
    rope_table<<<(SEG * DH) / 256, 256, 0, stream>>>(rtab);
    fill_pmem_pad<<<(NSH * PMEMN * DH) / 256, 256, 0, stream>>>(pmem, kpadb, vtpadb);
    gemm_qkv_ep<<<dim3(TOK / 128, NQKV / 128), 256, 0, stream>>>(xn, wqkvT, rtab, qbuf, kpadb, vtpadb, origv);
    flash_attn<<<4 * NSH, 256, 0, stream>>>(qbuf, kpadb, vtpadb, attno);
    gemm_bt<float><<<dim3(TOK / 128, DIM / 128), 256, 0, stream>>>(attno, woutT, out, TOK, DIM, DIM);
}

// Round 2
// 241.640 us; speedup vs baseline: 1.1123x; 1.1123x over previous
//
#include <hip/hip_runtime.h>
#include <hip/hip_bf16.h>

#define DIM    1024
#define HEADS  16
#define DH     64
#define SEG    512
#define PMEMN  16
#define TOK    8192        // 2*4096 tokens = 16 segments * 512
#define NQKV   3072
#define JPAD   544         // PMEM + SEG + 16 zero-pad (17 tiles of 32)
#define NSH    256         // 16 segments * 16 heads
#define VTS    129         // v-transpose LDS row stride (odd -> no 16-way bank conflict)
#define QKS    136         // q/k bf16 stage row stride (272B: 16B-aligned, quads on disjoint octets)
#define VFS    132         // v fp32 stage row stride (528B: 16B-aligned, quads conflict-free)

typedef __hip_bfloat16 bf16;
typedef __attribute__((ext_vector_type(8))) short short8;   // 8 bf16 = 4 VGPRs
typedef __attribute__((ext_vector_type(4))) float floatx4;  // MFMA C/D frag

__device__ __forceinline__ short8 ld_frag(const bf16* p) {
    return *(const short8*)p;
}
__device__ __forceinline__ floatx4 mfma16(short8 a, short8 b, floatx4 c) {
    return __builtin_amdgcn_mfma_f32_16x16x32_bf16(a, b, c, 0, 0, 0);
}
// async global->LDS DMA, 16 B per lane; LDS dest must be wave base + lane*16
__device__ __forceinline__ void g2lds16(const bf16* g, bf16* l) {
    __builtin_amdgcn_global_load_lds((const __attribute__((address_space(1))) void*)g,
                                     (__attribute__((address_space(3))) void*)l, 16, 0, 0);
}

// ---------------- RMSNorm: fp32 in -> bf16 normalized ----------------
__global__ void rmsnorm_kernel(const float* __restrict__ x, const float* __restrict__ wgt,
                               bf16* __restrict__ xn) {
    int row = blockIdx.x;
    int tid = threadIdx.x;              // 256 threads, 4 floats each
    const float4* xr = (const float4*)(x + (long)row * DIM);
    float4 v = xr[tid];
    float ss = v.x * v.x + v.y * v.y + v.z * v.z + v.w * v.w;
    #pragma unroll
    for (int off = 32; off; off >>= 1) ss += __shfl_xor(ss, off);
    __shared__ float red[4];
    if ((tid & 63) == 0) red[tid >> 6] = ss;
    __syncthreads();
    float tot = red[0] + red[1] + red[2] + red[3];
    float sc = rsqrtf(tot * (1.0f / DIM) + 1.1920929e-07f);
    const float4* wr = (const float4*)wgt;
    float4 w4 = wr[tid];
    bf16* o = xn + (long)row * DIM + tid * 4;
    o[0] = __float2bfloat16(v.x * sc * w4.x);
    o[1] = __float2bfloat16(v.y * sc * w4.y);
    o[2] = __float2bfloat16(v.z * sc * w4.z);
    o[3] = __float2bfloat16(v.w * sc * w4.w);
}

// ---- merged transpose + cast: wqkv [1024][3072] and wout [1024][1024] -> bf16 [C][R] ----
__global__ void transpose_w2(const float* __restrict__ wqkv, const float* __restrict__ wout,
                             bf16* __restrict__ wqkvT, bf16* __restrict__ woutT) {
    __shared__ float tile[32][33];
    int bx = blockIdx.x;
    const float* in; bf16* out; int C, c0;
    if (bx < 96) { in = wqkv; out = wqkvT; C = NQKV; c0 = bx * 32; }
    else         { in = wout; out = woutT; C = DIM;  c0 = (bx - 96) * 32; }
    const int R = DIM;
    int r0 = blockIdx.y * 32;
    int tx = threadIdx.x, ty = threadIdx.y;      // (32,8)
    #pragma unroll
    for (int i = 0; i < 4; i++)
        tile[ty + i * 8][tx] = in[(long)(r0 + ty + i * 8) * C + c0 + tx];
    __syncthreads();
    #pragma unroll
    for (int i = 0; i < 4; i++)
        out[(long)(c0 + ty + i * 8) * R + r0 + tx] = __float2bfloat16(tile[tx][ty + i * 8]);
}

// ------- out-projection GEMM: C[M][N] = A[M][K]*Bt[N][K]^T, fp32 out via LDS stage -------
__global__ __launch_bounds__(256)
void gemm_bt_f(const bf16* __restrict__ A, const bf16* __restrict__ Bt,
               float* __restrict__ C, int M, int N, int K) {
    __shared__ __align__(16) bf16 SMu[128 * 136];    // 34816 B; K-loop uses first 32 KB
    bf16* As = SMu;
    bf16* Bs = SMu + 128 * 64;
    const int tid = threadIdx.x;
    const int wv = tid >> 6;
    const int lane = tid & 63;
    const int quad = lane >> 4, l15 = lane & 15;
    const int wm = (wv >> 1) * 64, wn = (wv & 1) * 64;
    const int bm = blockIdx.x, bn = blockIdx.y;

    const int srow = tid >> 3;
    const int sgch = (tid & 7) ^ (srow & 7);
    const bf16* Ag = A + (long)(bm * 128 + srow) * K + sgch * 8;
    const bf16* Bg = Bt + (long)(bn * 128 + srow) * K + sgch * 8;
    const long row32 = (long)32 * K;

    const int rx0 = ((0 + quad) ^ (l15 & 7)) * 8;
    const int rx1 = ((4 + quad) ^ (l15 & 7)) * 8;

    floatx4 acc[4][4] = {};

    for (int k0 = 0; k0 < K; k0 += 64) {
        __syncthreads();
        #pragma unroll
        for (int i = 0; i < 4; i++) {
            g2lds16(Ag + i * row32 + k0, As + i * 2048 + tid * 8);
            g2lds16(Bg + i * row32 + k0, Bs + i * 2048 + tid * 8);
        }
        __syncthreads();
        #pragma unroll
        for (int kk = 0; kk < 2; kk++) {
            const int rx = kk ? rx1 : rx0;
            short8 af[4], bfr[4];
            #pragma unroll
            for (int i = 0; i < 4; i++) af[i] = ld_frag(&As[(wm + i * 16 + l15) * 64 + rx]);
            #pragma unroll
            for (int j = 0; j < 4; j++) bfr[j] = ld_frag(&Bs[(wn + j * 16 + l15) * 64 + rx]);
            #pragma unroll
            for (int i = 0; i < 4; i++)
                #pragma unroll
                for (int j = 0; j < 4; j++)
                    acc[i][j] = mfma16(af[i], bfr[j], acc[i][j]);
        }
    }
    // ---- fp32 C-write via LDS half-staging: full-line float4 stores ----
    float* SMf = (float*)SMu;            // 64 x VFS fp32 = 33792 B
    #pragma unroll
    for (int half = 0; half < 2; half++) {
        __syncthreads();                 // half0: also guards As/Bs reuse
        if ((wv >> 1) == half) {
            #pragma unroll
            for (int i = 0; i < 4; i++)
                #pragma unroll
                for (int j = 0; j < 4; j++)
                    #pragma unroll
                    for (int r = 0; r < 4; r++)
                        SMf[(i * 16 + quad * 4 + r) * VFS + wn + j * 16 + l15] = acc[i][j][r];
        }
        __syncthreads();
        #pragma unroll
        for (int it = 0; it < 8; it++) {
            int cid = it * 256 + tid;
            int rr = cid >> 5, cc = cid & 31;          // 64 rows x 32 float4-chunks
            float4 v4 = *(const float4*)&SMf[rr * VFS + cc * 4];
            *(float4*)&C[(long)(bm * 128 + half * 64 + rr) * N + bn * 128 + cc * 4] = v4;
        }
    }
}

// ------- QKV GEMM with fused epilogue: rope(q)->qbuf, rope(k)->kpad, v->origv+vtpad -------
__global__ __launch_bounds__(256)
void gemm_qkv_ep(const bf16* __restrict__ A, const bf16* __restrict__ Bt,
                 bf16* __restrict__ qbuf, bf16* __restrict__ kpad,
                 bf16* __restrict__ vtpad, float* __restrict__ origv) {
    const int K = DIM, N = NQKV;
    __shared__ __align__(16) bf16 SM[128 * 136];   // 34816 B; K-loop uses first 32 KB
    bf16* As = SM;
    bf16* Bs = SM + 128 * 64;
    const int tid = threadIdx.x;
    const int wv = tid >> 6;
    const int lane = tid & 63;
    const int quad = lane >> 4, l15 = lane & 15;
    const int wm = (wv >> 1) * 64, wn = (wv & 1) * 64;
    const int bm = blockIdx.x, bn = blockIdx.y;

    const int strow = tid >> 3;
    const int sgch = (tid & 7) ^ (strow & 7);
    const bf16* Ag = A + (long)(bm * 128 + strow) * K + sgch * 8;
    const bf16* Bg = Bt + (long)(bn * 128 + strow) * K + sgch * 8;
    const long row32 = (long)32 * K;

    const int rx0 = ((0 + quad) ^ (l15 & 7)) * 8;
    const int rx1 = ((4 + quad) ^ (l15 & 7)) * 8;

    floatx4 acc[4][4] = {};

    for (int k0 = 0; k0 < K; k0 += 64) {
        __syncthreads();
        #pragma unroll
        for (int i = 0; i < 4; i++) {
            g2lds16(Ag + i * row32 + k0, As + i * 2048 + tid * 8);
            g2lds16(Bg + i * row32 + k0, Bs + i * 2048 + tid * 8);
        }
        __syncthreads();
        #pragma unroll
        for (int kk = 0; kk < 2; kk++) {
            const int rx = kk ? rx1 : rx0;
            short8 af[4], bfr[4];
            #pragma unroll
            for (int i = 0; i < 4; i++) af[i] = ld_frag(&As[(wm + i * 16 + l15) * 64 + rx]);
            #pragma unroll
            for (int j = 0; j < 4; j++) bfr[j] = ld_frag(&Bs[(wn + j * 16 + l15) * 64 + rx]);
            #pragma unroll
            for (int i = 0; i < 4; i++)
                #pragma unroll
                for (int j = 0; j < 4; j++)
                    acc[i][j] = mfma16(af[i], bfr[j], acc[i][j]);
        }
    }

    const int tok0 = bm * 128;
    const int seg = tok0 >> 9;          // block fully inside one segment
    const int s0 = tok0 & 511;

    if (bn < 16) {
        // ---- q or k block: rope in-register, stage bf16 in LDS, vector stores ----
        const bool isq = (bn < 8);
        __syncthreads();                 // all waves done reading As/Bs
        #pragma unroll
        for (int j = 0; j < 4; j++) {
            int col = wn + j * 16 + l15;                 // local col 0..127
            int dcol = (bn * 128 + col) & 1023;          // within q or k
            int dh = dcol & 63;
            int pr = dh >> 1;
            float invf = __expf(-(float)pr * (9.210340371976184f / 32.0f));
            const bool odd = dh & 1;
            #pragma unroll
            for (int i = 0; i < 4; i++)
                #pragma unroll
                for (int r = 0; r < 4; r++) {
                    int sl = s0 + wm + i * 16 + quad * 4 + r;   // s within segment
                    float sn, cs;
                    __sincosf((float)sl * invf, &sn, &cs);
                    float v = acc[i][j][r];
                    float px = __shfl_xor(v, 1);
                    float y = odd ? (v * cs + px * sn) : (v * cs - px * sn);
                    if (isq) y *= 0.125f;                // fold DH^-0.5 (exact)
                    SM[(wm + i * 16 + quad * 4 + r) * QKS + col] = __float2bfloat16(y);
                }
        }
        __syncthreads();
        #pragma unroll
        for (int it = 0; it < 8; it++) {
            int cid = it * 256 + tid;
            int rr = cid >> 4, cc = cid & 15;            // 128 rows x 16 short8-chunks
            short8 pk = *(const short8*)&SM[rr * QKS + cc * 8];
            if (isq) {
                *(short8*)&qbuf[(long)(tok0 + rr) * DIM + bn * 128 + cc * 8] = pk;
            } else {
                int lc = cc * 8;
                int h = ((bn - 8) * 128 + lc) >> 6;
                int dh = lc & 63;
                *(short8*)&kpad[(((long)(seg * 16 + h) * JPAD) + PMEMN + s0 + rr) * DH + dh] = pk;
            }
        }
    } else {
        // ---- v block: origv fp32 via LDS half-staging + bf16 LDS transpose -> vtpad ----
        const int vq = bn - 16;
        const int h0 = vq * 2;                           // 2 heads per 128-col block
        float* SMf = (float*)SM;                         // 64 x VFS fp32
        #pragma unroll
        for (int half = 0; half < 2; half++) {
            __syncthreads();             // half0: also guards As/Bs reuse
            if ((wv >> 1) == half) {     // waves holding rows half*64 .. half*64+63
                #pragma unroll
                for (int i = 0; i < 4; i++)
                    #pragma unroll
                    for (int j = 0; j < 4; j++)
                        #pragma unroll
                        for (int r = 0; r < 4; r++)
                            SMf[(i * 16 + quad * 4 + r) * VFS + wn + j * 16 + l15] = acc[i][j][r];
            }
            __syncthreads();
            #pragma unroll
            for (int it = 0; it < 8; it++) {
                int cid = it * 256 + tid;
                int rr = cid >> 5, cc = cid & 31;        // 64 rows x 32 float4-chunks
                int h = h0 + (cc >> 4), dh = (cc * 4) & 63;
                float4 v4 = *(const float4*)&SMf[rr * VFS + cc * 4];
                int sl = s0 + half * 64 + rr;
                *(float4*)&origv[((long)(seg * 16 + h) * SEG + sl) * DH + dh] = v4;
            }
        }
        __syncthreads();
        // row stride VTS=129 (odd): column read below spreads over banks (2-way, free)
        #pragma unroll
        for (int i = 0; i < 4; i++)
            #pragma unroll
            for (int j = 0; j < 4; j++)
                #pragma unroll
                for (int r = 0; r < 4; r++)
                    SM[(wm + i * 16 + quad * 4 + r) * VTS + wn + j * 16 + l15] =
                        __float2bfloat16(acc[i][j][r]);
        __syncthreads();
        #pragma unroll
        for (int it = 0; it < 8; it++) {
            int cid = it * 256 + tid;
            int orow = cid >> 4;          // local v-col 0..127
            int tch = cid & 15;           // token chunk of 8
            int vcol = vq * 128 + orow;
            int h = vcol >> 6, dh = vcol & 63;
            short8 pk;
            #pragma unroll
            for (int k = 0; k < 8; k++) {
                bf16 t = SM[(tch * 8 + k) * VTS + orow];
                pk[k] = __builtin_bit_cast(short, t);
            }
            *(short8*)&vtpad[(((long)(seg * 16 + h) * DH + dh) * JPAD) + PMEMN + s0 + tch * 8] = pk;
        }
    }
}

// ------------- pmem rows into kpad/vtpad + zero tail pad -------------
__global__ void fill_pmem_pad(const float* __restrict__ pmem, bf16* __restrict__ kpad,
                              bf16* __restrict__ vtpad) {
    int gid = blockIdx.x * 256 + threadIdx.x;
    int dh = gid & 63, j = (gid >> 6) & 15, sh = gid >> 10;
    int h = sh & 15;
    float kv = pmem[((0 * HEADS + h) * PMEMN + j) * DH + dh];
    float vv = pmem[((1 * HEADS + h) * PMEMN + j) * DH + dh];
    kpad[((long)sh * JPAD + j) * DH + dh] = __float2bfloat16(kv);
    vtpad[((long)sh * DH + dh) * JPAD + j] = __float2bfloat16(vv);
    kpad[((long)sh * JPAD + PMEMN + SEG + j) * DH + dh] = __float2bfloat16(0.0f);
    vtpad[((long)sh * DH + dh) * JPAD + PMEMN + SEG + j] = __float2bfloat16(0.0f);
}

// ------- flash attention v3: 1 wave = 32 q rows, NO block barriers in K-loop -------
__global__ __launch_bounds__(256, 3)
void flash_attn(const bf16* __restrict__ qbuf, const bf16* __restrict__ kpad,
                const bf16* __restrict__ vtpad, bf16* __restrict__ attn_out) {
    const int bid = blockIdx.x;
    const int sh = bid & (NSH - 1);
    const int qblk = bid >> 8;
    const int wv = threadIdx.x >> 6;
    const int lane = threadIdx.x & 63;
    const int quad = lane >> 4, l15 = lane & 15;
    const int qr0 = qblk * 128 + wv * 32;
    const int bw = sh >> 4, h = sh & 15;

    __shared__ __align__(16) short pbuf[4][32 * 32];   // per-wave P tile
    short* pb = pbuf[wv];

    const bf16* qr_g0 = qbuf + (long)(bw * SEG + qr0 + l15) * DIM + h * DH;
    const bf16* qr_g1 = qbuf + (long)(bw * SEG + qr0 + 16 + l15) * DIM + h * DH;
    short8 aq[2][2] = {{ld_frag(qr_g0 + quad * 8), ld_frag(qr_g0 + 32 + quad * 8)},
                       {ld_frag(qr_g1 + quad * 8), ld_frag(qr_g1 + 32 + quad * 8)}};

    // ones B-fragment: B[k][0]=1 -> D[:,0] = row-sum of P
    const short bf16one = (short)0x3F80;
    short8 onesB;
    #pragma unroll
    for (int i = 0; i < 8; i++) onesB[i] = (l15 == 0) ? bf16one : (short)0;

    float mrow[2][4];
    floatx4 o[2][4] = {};
    floatx4 lac[2] = {};
    #pragma unroll
    for (int g = 0; g < 2; g++)
        #pragma unroll
        for (int r = 0; r < 4; r++) mrow[g][r] = -1e30f;

    const bf16* kb = kpad + (long)sh * JPAD * DH;
    const bf16* vbp = vtpad + (long)sh * DH * JPAD;

    const int ntiles = (qr0 + 47) / 32 + 1;

    short8 kf[4];
    {
        const bf16* kr0 = kb + (long)l15 * DH;
        const bf16* kr1 = kb + (long)(16 + l15) * DH;
        kf[0] = ld_frag(kr0 + quad * 8);  kf[1] = ld_frag(kr0 + 32 + quad * 8);
        kf[2] = ld_frag(kr1 + quad * 8);  kf[3] = ld_frag(kr1 + 32 + quad * 8);
    }

    for (int jt = 0; jt < ntiles; ++jt) {
        const int j0 = jt * 32;
        short8 bv[4];
        #pragma unroll
        for (int n = 0; n < 4; n++)
            bv[n] = ld_frag(vbp + (long)(n * 16 + l15) * JPAD + j0 + quad * 8);

        floatx4 sc[2][2];
        #pragma unroll
        for (int g = 0; g < 2; g++) {
            sc[g][0] = mfma16(aq[g][1], kf[1], mfma16(aq[g][0], kf[0], floatx4{}));
            sc[g][1] = mfma16(aq[g][1], kf[3], mfma16(aq[g][0], kf[2], floatx4{}));
        }
        {
            const int jn = (jt + 1 < ntiles) ? j0 + 32 : j0;
            const bf16* kr0 = kb + (long)(jn + l15) * DH;
            const bf16* kr1 = kb + (long)(jn + 16 + l15) * DH;
            kf[0] = ld_frag(kr0 + quad * 8);  kf[1] = ld_frag(kr0 + 32 + quad * 8);
            kf[2] = ld_frag(kr1 + quad * 8);  kf[3] = ld_frag(kr1 + 32 + quad * 8);
        }

        float alpha[2][4];
        #pragma unroll
        for (int g = 0; g < 2; g++) {
            #pragma unroll
            for (int r = 0; r < 4; r++) {
                int qi = qr0 + g * 16 + quad * 4 + r;
                int ja = j0 + l15;
                int jb = j0 + 16 + l15;
                float va  = ((ja < PMEMN) || (ja - PMEMN <= qi)) ? sc[g][0][r] : -1e30f;
                float vb2 = ((jb < PMEMN) || (jb - PMEMN <= qi)) ? sc[g][1][r] : -1e30f;
                float rm = fmaxf(va, vb2);
                #pragma unroll
                for (int off = 1; off < 16; off <<= 1) rm = fmaxf(rm, __shfl_xor(rm, off));
                float mn = fmaxf(mrow[g][r], rm);
                alpha[g][r] = __expf(mrow[g][r] - mn);
                mrow[g][r] = mn;
                float p0 = __expf(va - mn);
                float p1 = __expf(vb2 - mn);
                pb[(g * 16 + quad * 4 + r) * 32 + l15]      = __builtin_bit_cast(short, __float2bfloat16(p0));
                pb[(g * 16 + quad * 4 + r) * 32 + 16 + l15] = __builtin_bit_cast(short, __float2bfloat16(p1));
            }
        }
        __asm__ volatile("" ::: "memory");
        short8 pa0, pa1;
        __builtin_memcpy(&pa0, &pb[l15 * 32 + quad * 8], 16);
        __builtin_memcpy(&pa1, &pb[(16 + l15) * 32 + quad * 8], 16);
        __asm__ volatile("" ::: "memory");
        #pragma unroll
        for (int r = 0; r < 4; r++) { lac[0][r] *= alpha[0][r]; lac[1][r] *= alpha[1][r]; }
        lac[0] = mfma16(pa0, onesB, lac[0]);
        lac[1] = mfma16(pa1, onesB, lac[1]);
        #pragma unroll
        for (int n = 0; n < 4; n++) {
            #pragma unroll
            for (int r = 0; r < 4; r++) { o[0][n][r] *= alpha[0][r]; o[1][n][r] *= alpha[1][r]; }
            o[0][n] = mfma16(pa0, bv[n], o[0][n]);
            o[1][n] = mfma16(pa1, bv[n], o[1][n]);
        }
    }
    #pragma unroll
    for (int g = 0; g < 2; g++) {
        bf16* orow = attn_out + (long)(bw * SEG + qr0 + g * 16 + quad * 4) * DIM + h * DH;
        #pragma unroll
        for (int r = 0; r < 4; r++) {
            float lsum = __shfl(lac[g][r], (lane & 48));
            float inv = 1.0f / lsum;
            #pragma unroll
            for (int n = 0; n < 4; n++)
                orow[(long)r * DIM + n * 16 + l15] = __float2bfloat16(o[g][n][r] * inv);
        }
    }
}

extern "C" void kernel_launch(void* const* d_in, const int* in_sizes, int n_in,
                              void* d_out, int out_size, void* d_ws, size_t ws_size,
                              hipStream_t stream) {
    const float* seq    = (const float*)d_in[0];
    const float* norm_w = (const float*)d_in[1];
    const float* w_qkv  = (const float*)d_in[2];
    const float* w_out  = (const float*)d_in[3];
    const float* pmem   = (const float*)d_in[4];
    // Reference outputs are FLOAT32: d_out = [out, orig_v] fp32.
    float* out   = (float*)d_out;
    float* origv = out + (long)TOK * DIM;

    char* p = (char*)d_ws;
    bf16* xn     = (bf16*)p; p += (long)TOK * DIM * 2;
    bf16* wqkvT  = (bf16*)p; p += (long)NQKV * DIM * 2;
    bf16* woutT  = (bf16*)p; p += (long)DIM * DIM * 2;
    bf16* qbuf   = (bf16*)p; p += (long)TOK * DIM * 2;
    bf16* kpadb  = (bf16*)p; p += (long)NSH * JPAD * DH * 2;
    bf16* vtpadb = (bf16*)p; p += (long)NSH * DH * JPAD * 2;
    bf16* attno  = xn;   // xn dead after QKV GEMM

    rmsnorm_kernel<<<TOK, 256, 0, stream>>>(seq, norm_w, xn);
    transpose_w2<<<dim3(128, 32), dim3(32, 8), 0, stream>>>(w_qkv, w_out, wqkvT, woutT);
    fill_pmem_pad<<<(NSH * PMEMN * DH) / 256, 256, 0, stream>>>(pmem, kpadb, vtpadb);
    gemm_qkv_ep<<<dim3(TOK / 128, NQKV / 128), 256, 0, stream>>>(xn, wqkvT, qbuf, kpadb, vtpadb, origv);
    flash_attn<<<4 * NSH, 256, 0, stream>>>(qbuf, kpadb, vtpadb, attno);
    gemm_bt_f<<<dim3(TOK / 128, DIM / 128), 256, 0, stream>>>(attno, woutT, out, TOK, DIM, DIM);
}